// Round 1
// baseline (599.890 us; speedup 1.0000x reference)
//
#include <hip/hip_runtime.h>
#include <stdint.h>

// ---------------------------------------------------------------------------
// scores[b,s] = v . tanh( hidden[b] @ Wh + bias + enc[s,b] @ We )
// out[b,s]   = softmax_s(scores)
// Factorization: hproj = hidden@Wh+bias (64x512, tiny);
//                big GEMM: enc_flat[M=65536,K=1024] @ We[K=1024,N=512] via bf16 MFMA,
//                epilogue reduces over N with tanh and v -> scalar per row.
// ---------------------------------------------------------------------------

typedef float  floatx4 __attribute__((ext_vector_type(4)));
typedef float  floatx8 __attribute__((ext_vector_type(8)));
typedef __bf16 bf16x8  __attribute__((ext_vector_type(8)));
typedef short  short8  __attribute__((ext_vector_type(8)));

union bfu { bf16x8 v; short8 s; };

#define LOG2E_X2 2.8853900817779268f

__device__ __forceinline__ void async_ld16(const void* g, void* l) {
  __builtin_amdgcn_global_load_lds(
      (const __attribute__((address_space(1))) void*)g,
      (__attribute__((address_space(3))) void*)l, 16, 0, 0);
}

// ---- kernel 0: W[512:1536,:] -> bf16, transposed to Wt[n][k]  (n<512, k<1024)
__global__ void wt_convert(const float* __restrict__ W, __bf16* __restrict__ Wt) {
  int idx = blockIdx.x * 256 + threadIdx.x;   // grid 2048 -> 524288 elems
  int n = idx & 511;
  int k = idx >> 9;
  // read coalesced over n; write strided (small, L2-absorbed)
  Wt[(long)n * 1024 + k] = (__bf16)W[(long)(512 + k) * 512 + n];
}

// ---- kernel 1: hproj[b][n] = bias[n] + sum_k hidden[b,k] * W[k,n]  (k<512)
// grid 256 blocks: b = blk>>2, k-chunk = blk&3 (128 k each); 512 threads = n
__global__ void hproj_kernel(const float* __restrict__ hidden,
                             const float* __restrict__ W,
                             const float* __restrict__ bias,
                             float* __restrict__ hproj) {
  const int tid = threadIdx.x;            // n
  const int b_  = blockIdx.x >> 2;
  const int kc  = blockIdx.x & 3;
  __shared__ float hid[128];
  if (tid < 128) hid[tid] = hidden[b_ * 512 + kc * 128 + tid];
  __syncthreads();
  float acc = (kc == 0) ? bias[tid] : 0.f;
  const float* Wp = W + (long)(kc * 128) * 512 + tid;
  #pragma unroll 8
  for (int k = 0; k < 128; k++) acc = fmaf(hid[k], Wp[(long)k * 512], acc);
  atomicAdd(&hproj[b_ * 512 + tid], acc);
}

// ---- kernel 2: the big GEMM + tanh/v-dot epilogue
// block = one s (64 rows m = s*64+b, b=row), 256 threads, full N=512.
// LDS layouts are chunk-major so both staging (global_load_lds, packed linear)
// and fragment reads (contiguous 16B per lane within a quad) are conflict-free.
__global__ __launch_bounds__(256, 2) void gemm_score(
    const float* __restrict__ enc,    // [M=65536][1024] fp32
    const __bf16* __restrict__ Wt,    // [512][1024] bf16 (n-major)
    const float* __restrict__ hproj,  // [64][512]
    const float* __restrict__ v,      // [512]
    float* __restrict__ scores)       // [64][1024]  ([b][s])
{
  __shared__ float  ldsA[2048];    // 8 KB : slot16B idx = c*128 + m*2 + h   (c<4,m<64,h<2)
  __shared__ __bf16 ldsB[16384];   // 32 KB: slot16B idx = c*512 + n         (c<4,n<512)
  __shared__ float  bscore[64];

  const int tid  = threadIdx.x;
  const int lane = tid & 63;
  const int wv   = tid >> 6;      // wave 0..3 -> n-range [wv*128, wv*128+128)
  const int q    = lane >> 4;     // quad 0..3
  const int t    = lane & 15;
  const long m0  = (long)blockIdx.x * 64;

  if (tid < 64) bscore[tid] = 0.f;

  floatx4 acc[4][8];              // [rt][ct] 16x16 tiles -> 128 VGPRs
  #pragma unroll
  for (int i = 0; i < 4; i++)
    #pragma unroll
    for (int j = 0; j < 8; j++)
      acc[i][j] = (floatx4){0.f, 0.f, 0.f, 0.f};

  for (int k0 = 0; k0 < 1024; k0 += 32) {
    __syncthreads();
    // stage A tile: 64 rows x 32 k fp32 (8 KB), 2 calls x 256 lanes x 16 B
    #pragma unroll
    for (int i = 0; i < 2; i++) {
      int idx = i * 256 + tid;
      int c = idx >> 7, m = (idx >> 1) & 63, h = idx & 1;
      async_ld16(enc + (m0 + m) * 1024 + k0 + c * 8 + h * 4, &ldsA[idx * 4]);
    }
    // stage B tile: 512 n x 32 k bf16 (32 KB), 8 calls
    #pragma unroll
    for (int i = 0; i < 8; i++) {
      int idx = i * 256 + tid;
      int c = idx >> 9, n = idx & 511;
      async_ld16(Wt + (long)n * 1024 + k0 + c * 8, &ldsB[idx * 8]);
    }
    __syncthreads();

    short8 afr[4], bfr[8];
    #pragma unroll
    for (int rt = 0; rt < 4; rt++) {
      // lane reads A[m=rt*16+t][k = q*8 + j], 8 consecutive fp32 (32 B, 2x b128)
      floatx8 av = *(const floatx8*)&ldsA[(q * 128 + (rt * 16 + t) * 2) * 4];
      union bfu u;
      #pragma unroll
      for (int j = 0; j < 8; j++) u.v[j] = (__bf16)av[j];
      afr[rt] = u.s;
    }
    #pragma unroll
    for (int ct = 0; ct < 8; ct++) {
      // lane reads B[k=q*8+j][n = wv*128+ct*16+t] = Wt[n][k0+q*8..+8], 16 B
      union bfu u;
      u.v = *(const bf16x8*)&ldsB[((long)q * 512 + wv * 128 + ct * 16 + t) * 8];
      bfr[ct] = u.s;
    }
    #pragma unroll
    for (int rt = 0; rt < 4; rt++)
      #pragma unroll
      for (int ct = 0; ct < 8; ct++)
        acc[rt][ct] = __builtin_amdgcn_mfma_f32_16x16x32_bf16(
            afr[rt], bfr[ct], acc[rt][ct], 0, 0, 0);
  }

  // ---- epilogue: score[row] = sum_n v[n] * tanh(acc + hproj[row][n])
  float vv[8];
  #pragma unroll
  for (int ct = 0; ct < 8; ct++) vv[ct] = v[wv * 128 + ct * 16 + t];

  #pragma unroll
  for (int rt = 0; rt < 4; rt++) {
    #pragma unroll
    for (int r = 0; r < 4; r++) {
      int row = rt * 16 + q * 4 + r;              // C/D: row=(lane>>4)*4+reg
      const float* hrow = hproj + row * 512 + wv * 128 + t;
      float s = 0.f;
      #pragma unroll
      for (int ct = 0; ct < 8; ct++) {
        float e  = acc[rt][ct][r] + hrow[ct * 16];
        float ex = __builtin_amdgcn_exp2f(e * LOG2E_X2);      // e^(2x)
        float th = 1.f - 2.f * __builtin_amdgcn_rcpf(ex + 1.f); // tanh(x)
        s = fmaf(vv[ct], th, s);
      }
      // reduce over the 16 lanes of the quad (cols); stays within quad
      s += __shfl_xor(s, 1);
      s += __shfl_xor(s, 2);
      s += __shfl_xor(s, 4);
      s += __shfl_xor(s, 8);
      if (t == 0) atomicAdd(&bscore[row], s);     // 4 waves accumulate
    }
  }
  __syncthreads();
  // row i of this block is b=i, s=blockIdx.x; write transposed [b][s]
  if (tid < 64) scores[(long)tid * 1024 + blockIdx.x] = bscore[tid];
}

// ---- kernel 3: softmax over s for each b
__global__ void softmax_kernel(const float* __restrict__ scores,
                               float* __restrict__ out) {
  const int b_   = blockIdx.x;
  const int tid  = threadIdx.x;
  const int lane = tid & 63;
  const int wv   = tid >> 6;
  __shared__ float redmax[4], redsum[4];

  float x[4];
  #pragma unroll
  for (int i = 0; i < 4; i++) x[i] = scores[b_ * 1024 + i * 256 + tid];
  float mx = fmaxf(fmaxf(x[0], x[1]), fmaxf(x[2], x[3]));
  #pragma unroll
  for (int off = 1; off < 64; off <<= 1) mx = fmaxf(mx, __shfl_xor(mx, off));
  if (lane == 0) redmax[wv] = mx;
  __syncthreads();
  mx = fmaxf(fmaxf(redmax[0], redmax[1]), fmaxf(redmax[2], redmax[3]));

  float e[4], s = 0.f;
  #pragma unroll
  for (int i = 0; i < 4; i++) { e[i] = __expf(x[i] - mx); s += e[i]; }
  #pragma unroll
  for (int off = 1; off < 64; off <<= 1) s += __shfl_xor(s, off);
  if (lane == 0) redsum[wv] = s;
  __syncthreads();
  s = redsum[0] + redsum[1] + redsum[2] + redsum[3];
  float inv = 1.f / s;
  #pragma unroll
  for (int i = 0; i < 4; i++) out[b_ * 1024 + i * 256 + tid] = e[i] * inv;
}

extern "C" void kernel_launch(void* const* d_in, const int* in_sizes, int n_in,
                              void* d_out, int out_size, void* d_ws, size_t ws_size,
                              hipStream_t stream) {
  (void)in_sizes; (void)n_in; (void)out_size; (void)ws_size;
  const float* hidden = (const float*)d_in[0];   // [64,512]
  const float* enc    = (const float*)d_in[1];   // [1024,64,1024]
  const float* W      = (const float*)d_in[2];   // [1536,512]
  const float* bias   = (const float*)d_in[3];   // [512]
  const float* v      = (const float*)d_in[4];   // [512]
  float* out = (float*)d_out;                    // [64,1024]

  char* ws = (char*)d_ws;
  __bf16* Wt    = (__bf16*)ws;                          // 1 MB
  float*  hproj = (float*)(ws + (1 << 20));             // 128 KB
  float*  scores= (float*)(ws + (1 << 20) + (128 << 10)); // 256 KB

  hipMemsetAsync(hproj, 0, 64 * 512 * sizeof(float), stream);
  wt_convert<<<2048, 256, 0, stream>>>(W, Wt);
  hproj_kernel<<<256, 512, 0, stream>>>(hidden, W, bias, hproj);
  gemm_score<<<1024, 256, 0, stream>>>(enc, Wt, hproj, v, scores);
  softmax_kernel<<<64, 256, 0, stream>>>(scores, out);
}

// Round 2
// 491.807 us; speedup vs baseline: 1.2198x; 1.2198x over previous
//
#include <hip/hip_runtime.h>
#include <stdint.h>

// ---------------------------------------------------------------------------
// scores[b,s] = v . tanh( hidden[b] @ Wh + bias + enc[s,b] @ We )
// out[b,s]   = softmax_s(scores)
// Big GEMM: enc_flat[M=65536,K=1024] @ We[K=1024,N=512], bf16 MFMA.
// R2: pipelined K-loop — A async->LDS double-buffered, B global->VGPR
//     prefetched 1 iter ahead; single barrier per K-step (drain overlaps
//     fragread+MFMA instead of being fully exposed as in R1).
// ---------------------------------------------------------------------------

typedef float  floatx4 __attribute__((ext_vector_type(4)));
typedef float  floatx8 __attribute__((ext_vector_type(8)));
typedef __bf16 bf16x8  __attribute__((ext_vector_type(8)));
typedef short  short8  __attribute__((ext_vector_type(8)));

union bfu { bf16x8 v; short8 s; };

#define LOG2E_X2 2.8853900817779268f

__device__ __forceinline__ void async_ld16(const void* g, void* l) {
  __builtin_amdgcn_global_load_lds(
      (const __attribute__((address_space(1))) void*)g,
      (__attribute__((address_space(3))) void*)l, 16, 0, 0);
}

// ---- kernel 0: W[512:1536,:] -> bf16 transposed Wt[n][k], LDS-tiled 64x64.
// R1 version did 2-byte writes at stride 2KB (suspected ~200us). Now both
// sides coalesced: 256B reads, 128B contiguous bf16 writes.
__global__ void wt_convert(const float* __restrict__ W, __bf16* __restrict__ Wt) {
  __shared__ float tile[64][65];                 // +1 pad: conflict-free both ways
  const int kt = blockIdx.x >> 3;                // 16 k-tiles
  const int nt = blockIdx.x & 7;                 // 8 n-tiles
  const int c  = threadIdx.x & 63;
  const int r4 = threadIdx.x >> 6;               // 4 rows per pass
  #pragma unroll 4
  for (int i = 0; i < 16; i++) {
    int r = i * 4 + r4;                          // k-local
    tile[r][c] = W[(long)(512 + kt * 64 + r) * 512 + nt * 64 + c];
  }
  __syncthreads();
  #pragma unroll 4
  for (int i = 0; i < 16; i++) {
    int n = i * 4 + r4;                          // n-local; lane c = k-local
    Wt[(long)(nt * 64 + n) * 1024 + kt * 64 + c] = (__bf16)tile[c][n];
  }
}

// ---- kernel 1: hproj[b][n] = bias[n] + sum_k hidden[b,k] * W[k,n]  (k<512)
__global__ void hproj_kernel(const float* __restrict__ hidden,
                             const float* __restrict__ W,
                             const float* __restrict__ bias,
                             float* __restrict__ hproj) {
  const int tid = threadIdx.x;            // n
  const int b_  = blockIdx.x >> 2;
  const int kc  = blockIdx.x & 3;
  __shared__ float hid[128];
  if (tid < 128) hid[tid] = hidden[b_ * 512 + kc * 128 + tid];
  __syncthreads();
  float acc = (kc == 0) ? bias[tid] : 0.f;
  const float* Wp = W + (long)(kc * 128) * 512 + tid;
  #pragma unroll 8
  for (int k = 0; k < 128; k++) acc = fmaf(hid[k], Wp[(long)k * 512], acc);
  atomicAdd(&hproj[b_ * 512 + tid], acc);
}

// ---- kernel 2: the big GEMM + tanh/v-dot epilogue, pipelined
__global__ __launch_bounds__(256, 2) void gemm_score(
    const float* __restrict__ enc,    // [65536][1024] fp32
    const __bf16* __restrict__ Wt,    // [512][1024] bf16 (n-major)
    const float* __restrict__ hproj,  // [64][512]
    const float* __restrict__ v,      // [512]
    float* __restrict__ scores)       // [64][1024]  ([b][s])
{
  __shared__ float ldsA0[2048];    // 8 KB: A tile 64m x 32k fp32, slot16B idx = c*128+m*2+h
  __shared__ float ldsA1[2048];    // double buffer
  __shared__ float bscore[64];

  const int tid  = threadIdx.x;
  const int lane = tid & 63;
  const int wv   = tid >> 6;      // wave -> n-range [wv*128, wv*128+128)
  const int q    = lane >> 4;
  const int t    = lane & 15;
  const long m0  = (long)blockIdx.x * 64;

  // per-lane B base: Wt[n = wv*128 + ct*16 + t][k0 + q*8 ...], 16B per load
  const __bf16* bp = Wt + (long)(wv * 128 + t) * 1024 + q * 8;

  if (tid < 64) bscore[tid] = 0.f;

  floatx4 acc[4][8];
  #pragma unroll
  for (int i = 0; i < 4; i++)
    #pragma unroll
    for (int j = 0; j < 8; j++)
      acc[i][j] = (floatx4){0.f, 0.f, 0.f, 0.f};

  auto issueA = [&](int kk, float* buf) {
    #pragma unroll
    for (int i = 0; i < 2; i++) {
      int idx = i * 256 + tid;
      int c = idx >> 7, m = (idx >> 1) & 63, h = idx & 1;
      async_ld16(enc + (m0 + m) * 1024 + kk + c * 8 + h * 4, buf + idx * 4);
    }
  };
  auto loadB = [&](int kk, short8* br) {
    #pragma unroll
    for (int ct = 0; ct < 8; ct++) {
      union bfu u;
      u.v = *(const bf16x8*)(bp + kk + ct * 16 * 1024);
      br[ct] = u.s;
    }
  };
  auto fragA = [&](const float* buf, short8* af) {
    #pragma unroll
    for (int rt = 0; rt < 4; rt++) {
      floatx8 av = *(const floatx8*)(buf + (q * 128 + (rt * 16 + t) * 2) * 4);
      union bfu u;
      #pragma unroll
      for (int j = 0; j < 8; j++) u.v[j] = (__bf16)av[j];
      af[rt] = u.s;
    }
  };
  auto domfma = [&](short8* af, short8* br) {
    #pragma unroll
    for (int rt = 0; rt < 4; rt++)
      #pragma unroll
      for (int ct = 0; ct < 8; ct++)
        acc[rt][ct] = __builtin_amdgcn_mfma_f32_16x16x32_bf16(
            af[rt], br[ct], acc[rt][ct], 0, 0, 0);
  };

  short8 b0[8], b1[8], afr[4];

  // prologue: stage k-step 0
  issueA(0, ldsA0);
  loadB(0, b0);
  __syncthreads();                 // compiler drains vmcnt(0) here — once

  // 32 K-steps of 32, manually unrolled 2x for register ping-pong.
  // Each phase: prefetch next step (A async->other LDS buf, B->other regs),
  // then fragread+MFMA current, then barrier (drain overlaps the compute).
  for (int T = 0; T < 16; T++) {
    const int kk = T * 64;
    issueA(kk + 32, ldsA1);
    loadB(kk + 32, b1);
    fragA(ldsA0, afr);
    domfma(afr, b0);
    __syncthreads();

    if (T < 15) {                  // last odd phase has no successor
      issueA(kk + 64, ldsA0);
      loadB(kk + 64, b0);
    }
    fragA(ldsA1, afr);
    domfma(afr, b1);
    __syncthreads();
  }

  // ---- epilogue: score[row] = sum_n v[n] * tanh(acc + hproj[row][n])
  float vv[8];
  #pragma unroll
  for (int ct = 0; ct < 8; ct++) vv[ct] = v[wv * 128 + ct * 16 + t];

  #pragma unroll
  for (int rt = 0; rt < 4; rt++) {
    #pragma unroll
    for (int r = 0; r < 4; r++) {
      int row = rt * 16 + q * 4 + r;              // C/D: row=(lane>>4)*4+reg
      const float* hrow = hproj + row * 512 + wv * 128 + t;
      float s = 0.f;
      #pragma unroll
      for (int ct = 0; ct < 8; ct++) {
        float e  = acc[rt][ct][r] + hrow[ct * 16];
        float ex = __builtin_amdgcn_exp2f(e * LOG2E_X2);        // e^(2x)
        float th = 1.f - 2.f * __builtin_amdgcn_rcpf(ex + 1.f); // tanh(x)
        s = fmaf(vv[ct], th, s);
      }
      s += __shfl_xor(s, 1);
      s += __shfl_xor(s, 2);
      s += __shfl_xor(s, 4);
      s += __shfl_xor(s, 8);
      if (t == 0) atomicAdd(&bscore[row], s);
    }
  }
  __syncthreads();
  if (tid < 64) scores[(long)tid * 1024 + blockIdx.x] = bscore[tid];
}

// ---- kernel 3: softmax over s for each b
__global__ void softmax_kernel(const float* __restrict__ scores,
                               float* __restrict__ out) {
  const int b_   = blockIdx.x;
  const int tid  = threadIdx.x;
  const int lane = tid & 63;
  const int wv   = tid >> 6;
  __shared__ float redmax[4], redsum[4];

  float x[4];
  #pragma unroll
  for (int i = 0; i < 4; i++) x[i] = scores[b_ * 1024 + i * 256 + tid];
  float mx = fmaxf(fmaxf(x[0], x[1]), fmaxf(x[2], x[3]));
  #pragma unroll
  for (int off = 1; off < 64; off <<= 1) mx = fmaxf(mx, __shfl_xor(mx, off));
  if (lane == 0) redmax[wv] = mx;
  __syncthreads();
  mx = fmaxf(fmaxf(redmax[0], redmax[1]), fmaxf(redmax[2], redmax[3]));

  float e[4], s = 0.f;
  #pragma unroll
  for (int i = 0; i < 4; i++) { e[i] = __expf(x[i] - mx); s += e[i]; }
  #pragma unroll
  for (int off = 1; off < 64; off <<= 1) s += __shfl_xor(s, off);
  if (lane == 0) redsum[wv] = s;
  __syncthreads();
  s = redsum[0] + redsum[1] + redsum[2] + redsum[3];
  float inv = 1.f / s;
  #pragma unroll
  for (int i = 0; i < 4; i++) out[b_ * 1024 + i * 256 + tid] = e[i] * inv;
}

extern "C" void kernel_launch(void* const* d_in, const int* in_sizes, int n_in,
                              void* d_out, int out_size, void* d_ws, size_t ws_size,
                              hipStream_t stream) {
  (void)in_sizes; (void)n_in; (void)out_size; (void)ws_size;
  const float* hidden = (const float*)d_in[0];   // [64,512]
  const float* enc    = (const float*)d_in[1];   // [1024,64,1024]
  const float* W      = (const float*)d_in[2];   // [1536,512]
  const float* bias   = (const float*)d_in[3];   // [512]
  const float* v      = (const float*)d_in[4];   // [512]
  float* out = (float*)d_out;                    // [64,1024]

  char* ws = (char*)d_ws;
  __bf16* Wt    = (__bf16*)ws;                            // 1 MB
  float*  hproj = (float*)(ws + (1 << 20));               // 128 KB
  float*  scores= (float*)(ws + (1 << 20) + (128 << 10)); // 256 KB

  hipMemsetAsync(hproj, 0, 64 * 512 * sizeof(float), stream);
  wt_convert<<<128, 256, 0, stream>>>(W, Wt);
  hproj_kernel<<<256, 512, 0, stream>>>(hidden, W, bias, hproj);
  gemm_score<<<1024, 256, 0, stream>>>(enc, Wt, hproj, v, scores);
  softmax_kernel<<<64, 256, 0, stream>>>(scores, out);
}